// Round 4
// baseline (463.900 us; speedup 1.0000x reference)
//
#include <hip/hip_runtime.h>
#include <hip/hip_bf16.h>

// BronxLayer fused implementation for MI355X (gfx950).  Round 9.
// r8: 434us; k3a 156us.  WRITE_SIZE fix confirmed (139->83 GB-KB) but LDS
// frag staging pushed VGPR 124->156, crossing the 128-VGPR occupancy cliff
// (waves/SIMD halved, occ 20->10.9%) -> net zero.  Root defect through
// r6/r8: eps/diff loads are issued and consumed in the SAME t-step (~900cy
// exposed HBM latency vs ~1000cy compute, no prefetch).
// Round-9 k3a: barrier-free r6 structure (direct kml fragment loads; 590MB
// L2 traffic = ~17us of L2 time, latency hidden under compute) + CROSS-T
// REGISTER PREFETCH of eps/diff (issue t+1 loads before computing t) +
// nontemporal on the 151MB eps stream (don't evict kml/hnT from L2).
// k3b: A-loads nontemporal (each apk byte read exactly once).  Everything
// else unchanged from r8.

#define NN 3072
#define HH 256
#define NB 4
#define HD 64
constexpr int KMLSZ = 192 * 2 * 64 * 8;  // shorts per (mat,head)

typedef __attribute__((ext_vector_type(8))) short bf16x8;
typedef __attribute__((ext_vector_type(4))) float f32x4;

static __device__ inline short f2bf(float f) {
    __hip_bfloat16 h = __float2bfloat16(f);
    return __builtin_bit_cast(short, h);
}

// ---------------- k0: weight prep + zero denom/klsum ----------------
__global__ void k0_prep(const float* __restrict__ Wk, const float* __restrict__ Wmu,
                        const float* __restrict__ Wls, const float* __restrict__ bk,
                        const float* __restrict__ bmu, const float* __restrict__ bls,
                        const float* __restrict__ Wv, short* __restrict__ WTcat,
                        float* __restrict__ biascat, short* __restrict__ WvT,
                        float* __restrict__ denom) {
    __shared__ float t[64][65];
    int bx = blockIdx.x;
    if (bx < 48) {
        int mat = bx >> 4;
        int by = (bx >> 2) & 3, bc = bx & 3;
        int y0 = by * 64, c0 = bc * 64;
        const float* W = (mat == 0) ? Wk : (mat == 1 ? Wmu : Wls);
        float scale = (mat == 0) ? 0.125f : 1.f;
        int r = threadIdx.x >> 4, c4 = (threadIdx.x & 15) * 4;
#pragma unroll
        for (int i = 0; i < 4; i++) {
            int yl = r + i * 16;
            float4 v = *(const float4*)(W + (y0 + yl) * 256 + c0 + c4);
            t[yl][c4] = v.x; t[yl][c4 + 1] = v.y; t[yl][c4 + 2] = v.z; t[yl][c4 + 3] = v.w;
        }
        __syncthreads();
#pragma unroll
        for (int i = 0; i < 4; i++) {
            int cl = r + i * 16;
            int corig = c0 + cl;
            int cp = mat * 256 + (corig & 3) * 64 + (corig >> 2);
            short4 v = make_short4(f2bf(t[c4][cl] * scale), f2bf(t[c4 + 1][cl] * scale),
                                   f2bf(t[c4 + 2][cl] * scale), f2bf(t[c4 + 3][cl] * scale));
            *(short4*)(WTcat + cp * 256 + y0 + c4) = v;
        }
        return;
    }
    if (bx < 112) {
        int b = bx - 48;
        int bk2 = b >> 2, bn = b & 3;
        int k0 = bk2 * 64, n0 = bn * 64;
        int r = threadIdx.x >> 4, c4 = (threadIdx.x & 15) * 4;
#pragma unroll
        for (int i = 0; i < 4; i++) {
            int kk = r + i * 16;
            float4 v = *(const float4*)(Wv + (k0 + kk) * 256 + n0 + c4);
            t[kk][c4] = v.x; t[kk][c4 + 1] = v.y; t[kk][c4 + 2] = v.z; t[kk][c4 + 3] = v.w;
        }
        __syncthreads();
#pragma unroll
        for (int i = 0; i < 4; i++) {
            int nn = r + i * 16;
            short4 v = make_short4(f2bf(t[c4][nn]), f2bf(t[c4 + 1][nn]),
                                   f2bf(t[c4 + 2][nn]), f2bf(t[c4 + 3][nn]));
            *(short4*)(WvT + (n0 + nn) * 1024 + k0 + c4) = v;
        }
        return;
    }
    if (bx == 112) {
        int cc = threadIdx.x;
        int corig = (cc & 63) * 4 + (cc >> 6);
        biascat[cc] = bk[corig] * 0.125f;
        biascat[256 + cc] = bmu[corig];
        biascat[512 + cc] = bls[corig];
        return;
    }
    int i = (bx - 113) * 256 + threadIdx.x;
    if (i < 13312) denom[i] = 0.f;   // denom[12288] then klsum[1024], contiguous
}

// ---------------- k1: LayerNorm ----------------
__global__ void k1_ln(const float* __restrict__ h, const float* __restrict__ gamma,
                      const float* __restrict__ beta, short* __restrict__ hn) {
    int row = blockIdx.x, tid = threadIdx.x;
    float v = h[row * 256 + tid];
    float s = v, s2 = v * v;
    for (int off = 32; off; off >>= 1) {
        s += __shfl_xor(s, off);
        s2 += __shfl_xor(s2, off);
    }
    __shared__ float red[8];
    int w = tid >> 6, lane = tid & 63;
    if (!lane) { red[w] = s; red[4 + w] = s2; }
    __syncthreads();
    s = red[0] + red[1] + red[2] + red[3];
    s2 = red[4] + red[5] + red[6] + red[7];
    float mean = s * (1.f / 256.f);
    float var = s2 * (1.f / 256.f) - mean * mean;
    float rs = rsqrtf(var + 1e-5f);
    hn[row * 256 + tid] = f2bf((v - mean) * rs * gamma[tid] + beta[tid]);
}

// ---------------- k1b: transpose hn -> hnT (LDS-tiled) ----------------
__global__ void k1b_tr(const short* __restrict__ hn, short* __restrict__ hnT) {
    __shared__ short t[64][68];
    int bn = blockIdx.x >> 2, bh = blockIdx.x & 3;
    int n0 = bn * 64, h0 = bh * 64;
    int r = threadIdx.x >> 4, c4 = (threadIdx.x & 15) * 4;
#pragma unroll
    for (int i = 0; i < 4; i++) {
        int nn = r + i * 16;
        *(short4*)&t[nn][c4] = *(const short4*)(hn + (n0 + nn) * 256 + h0 + c4);
    }
    __syncthreads();
#pragma unroll
    for (int i = 0; i < 4; i++) {
        int hh = r + i * 16;
        short4 v = make_short4(t[c4][hh], t[c4 + 1][hh], t[c4 + 2][hh], t[c4 + 3][hh]);
        *(short4*)(hnT + (h0 + hh) * NN + n0 + c4) = v;
    }
}

// ---------------- k2: projections (bf16 MFMA), fragment-packed output -----------
// kml packed per (mat,head): idx = ((zt*2 + khalf)*64 + lane)*8 + j
//   element: node z = zt*16 + (lane&15), k = khalf*32 + (lane>>4)*8 + j
__global__ __launch_bounds__(256) void k2_proj(const short* __restrict__ hn,
                                               const short* __restrict__ WTcat,
                                               const float* __restrict__ biascat,
                                               short* __restrict__ kml) {
    int bx = blockIdx.x;
    int mt = bx / 12, nb = bx % 12;
    int m0 = mt * 64, n0 = nb * 64;
    int tid = threadIdx.x, w = tid >> 6, lane = tid & 63, q = lane >> 4, c = lane & 15;
    int mrow = m0 + w * 16;
    f32x4 acc[4] = {{0, 0, 0, 0}, {0, 0, 0, 0}, {0, 0, 0, 0}, {0, 0, 0, 0}};
    for (int k0 = 0; k0 < 256; k0 += 32) {
        bf16x8 af = *(const bf16x8*)(hn + (mrow + c) * 256 + k0 + q * 8);
#pragma unroll
        for (int nt = 0; nt < 4; nt++) {
            bf16x8 bf = *(const bf16x8*)(WTcat + (n0 + nt * 16 + c) * 256 + k0 + q * 8);
            acc[nt] = __builtin_amdgcn_mfma_f32_16x16x32_bf16(af, bf, acc[nt], 0, 0, 0);
        }
    }
#pragma unroll
    for (int nt = 0; nt < 4; nt++) {
        int cp = n0 + nt * 16 + c;
        float bias = biascat[cp];
        int mat = cp >> 8, b = (cp >> 6) & 3, y = cp & 63;
        short* dst = kml + (size_t)(mat * 4 + b) * KMLSZ;
        int kh2 = y >> 5, lq = (y >> 3) & 3, j = y & 7;
        int zt = mt * 4 + w;  // m>>4
#pragma unroll
        for (int r = 0; r < 4; r++) {
            int ml = 4 * q + r;  // m&15
            dst[(((zt * 2 + kh2) * 64) + lq * 16 + ml) * 8 + j] = f2bf(acc[nt][r] + bias);
        }
    }
}

// ---------------- k3a: elementwise core (barrier-free + cross-t prefetch) -------
// Block: 64 x (wave w -> x-tile xb*4+w) x 64 z.  Waves fully independent:
// no LDS, no barriers (except final kl reduce).  Per t-step, eps/diff for
// t+1 are issued BEFORE computing t (register double-buffer) so the ~900cy
// HBM latency hides under the ~1000cy of MFMA+transcendental work.  mu/ls
// fragments load directly from kml (L2-resident, ~250cy, hidden likewise).
// Output a tile-packed: tile (b, xt, zt2) = 256 shorts at [c*16 + 4q + r].
__global__ __launch_bounds__(256) void k3a_elem(
    const short* __restrict__ kml, const float* __restrict__ eps,
    const float* __restrict__ diff, short* __restrict__ apk,
    float* __restrict__ denom, float* __restrict__ klsum) {
    __shared__ float klred[4];
    const int tid = threadIdx.x;
    const int w = tid >> 6, lane = tid & 63, q = lane >> 4, c = lane & 15;
    const int xb = blockIdx.x % 48;
    const int zc = blockIdx.x / 48;
    const int xt = xb * 4 + w;     // this wave's x-tile, 0..191
    const int x0 = xt * 16;

    // kh fragments (B-operand of S^T), hoisted: one per (head, k-half)
    bf16x8 qf[NB][2];
#pragma unroll
    for (int b = 0; b < NB; b++)
#pragma unroll
        for (int kh = 0; kh < 2; kh++)
            qf[b][kh] = *(const bf16x8*)(kml + (size_t)b * KMLSZ +
                                         ((xt * 2 + kh) * 64 + lane) * 8);

    float den_acc[NB] = {0.f, 0.f, 0.f, 0.f};
    float kl_acc = 0.f;
    const size_t xrow = (size_t)(x0 + c) * NN;

    // prologue: prefetch eps/diff for t=0
    f32x4 e_nxt[4];
    float d_nxt[4];
    {
        const int z16 = zc * 64;
#pragma unroll
        for (int r = 0; r < 4; r++) {
            e_nxt[r] = __builtin_nontemporal_load(
                (const f32x4*)(eps + (xrow + (size_t)(z16 + 4 * q + r)) * 4));
            d_nxt[r] = __builtin_nontemporal_load(diff + xrow + z16 + 4 * q + r);
        }
    }

#pragma unroll
    for (int t = 0; t < 4; t++) {
        const int zt2 = zc * 4 + t;
        // consume prefetched regs; immediately issue t+1 loads
        f32x4 e4[4];
        float dif[4];
#pragma unroll
        for (int r = 0; r < 4; r++) { e4[r] = e_nxt[r]; dif[r] = d_nxt[r]; }
        if (t < 3) {
            const int z16 = (zt2 + 1) * 16;
#pragma unroll
            for (int r = 0; r < 4; r++) {
                e_nxt[r] = __builtin_nontemporal_load(
                    (const f32x4*)(eps + (xrow + (size_t)(z16 + 4 * q + r)) * 4));
                d_nxt[r] = __builtin_nontemporal_load(diff + xrow + z16 + 4 * q + r);
            }
        }
#pragma unroll
        for (int b = 0; b < NB; b++) {
            const short* mup = kml + (size_t)(NB + b) * KMLSZ;
            const short* lsp = kml + (size_t)(2 * NB + b) * KMLSZ;
            bf16x8 a0 = *(const bf16x8*)(mup + ((zt2 * 2 + 0) * 64 + lane) * 8);
            bf16x8 a1 = *(const bf16x8*)(mup + ((zt2 * 2 + 1) * 64 + lane) * 8);
            bf16x8 l0 = *(const bf16x8*)(lsp + ((zt2 * 2 + 0) * 64 + lane) * 8);
            bf16x8 l1 = *(const bf16x8*)(lsp + ((zt2 * 2 + 1) * 64 + lane) * 8);
            f32x4 smu = {0.f, 0.f, 0.f, 0.f};
            smu = __builtin_amdgcn_mfma_f32_16x16x32_bf16(a0, qf[b][0], smu, 0, 0, 0);
            smu = __builtin_amdgcn_mfma_f32_16x16x32_bf16(a1, qf[b][1], smu, 0, 0, 0);
            f32x4 sls = {0.f, 0.f, 0.f, 0.f};
            sls = __builtin_amdgcn_mfma_f32_16x16x32_bf16(l0, qf[b][0], sls, 0, 0, 0);
            sls = __builtin_amdgcn_mfma_f32_16x16x32_bf16(l1, qf[b][1], sls, 0, 0, 0);
            short pk[4];
#pragma unroll
            for (int r = 0; r < 4; r++) {
                float mu = smu[r];
                float ls = sls[r];
                float e = e4[r][b];
                float d = dif[r];
                float ex = __expf(-fabsf(ls));
                float sg = fmaxf(ls, 0.f) + __logf(1.f + ex);
                float kle = -__logf(sg) + 0.5f * (sg * sg + mu * mu) - 0.5f;
                float sgn = (d > 0.f) ? 1.f : ((d < 0.f) ? -1.f : 0.f);
                kl_acc += sgn * kle;
                float av = __expf(mu + sg * e) * d;
                den_acc[b] += fabsf(av);
                pk[r] = f2bf(av);
            }
            // tile-packed store: wave writes 512B contiguous per (t,b)
            *(short4*)(apk + (((size_t)b * 192 + xt) * 192 + zt2) * 256 + c * 16 + q * 4) =
                make_short4(pk[0], pk[1], pk[2], pk[3]);
        }
    }
    // denominator: lane's elements all at x = x0 + c; reduce across quads
#pragma unroll
    for (int b = 0; b < NB; b++) {
        float d = den_acc[b];
        d += __shfl_down(d, 32);
        d += __shfl_down(d, 16);
        if (q == 0) atomicAdd(&denom[(x0 + c) * NB + b], d);
    }
    for (int off = 32; off; off >>= 1) kl_acc += __shfl_xor(kl_acc, off);
    if (lane == 0) klred[w] = kl_acc;
    __syncthreads();
    if (tid == 0) atomicAdd(klsum, klred[0] + klred[1] + klred[2] + klred[3]);
}

// ---------------- k3b: aggregation GEMM + normalize -> bf16 ----------------
// aggn[x, b*256+h] = (sum_z a_b[x,z] hnT[h,z]) / denom[x,b].  Block = 64m x
// 64n per head; waves split K 2-way (kw) x n 2-way (nw).  Barrier-free main
// loop (direct global loads: A tile-packed coalesced + nontemporal, B = hnT
// L2-resident); one LDS pair-reduce over kw at the end, then normalize.
__global__ __launch_bounds__(256) void k3b_agg(
    const short* __restrict__ apk, const short* __restrict__ hnT,
    const float* __restrict__ denom, short* __restrict__ aggn) {
    __shared__ float red[2][64 * 33];   // [nw][m*33 + nl], pad 33 vs bank conflicts
    const int tid = threadIdx.x;
    const int w = tid >> 6, lane = tid & 63, q = lane >> 4, c = lane & 15;
    const int kw = w >> 1, nw = w & 1;
    const int bid = blockIdx.x;
    const int b = bid & 3;
    const int nb = (bid >> 2) & 3;
    const int mb = bid >> 4;            // 0..47
    const int m0 = mb * 64;
    const int n0 = nb * 64 + nw * 32;
    const int q2 = q >> 1, q1 = q & 1;

    f32x4 acc[4][2];
#pragma unroll
    for (int i = 0; i < 4; i++)
#pragma unroll
        for (int j = 0; j < 2; j++) acc[i][j] = (f32x4){0.f, 0.f, 0.f, 0.f};

    const size_t abase = ((size_t)b * 192 + mb * 4) * 192 * 256;
    for (int ks = 0; ks < 48; ks++) {
        const int kglob = kw * 1536 + ks * 32;
        const int T2 = kw * 96 + ks * 2;   // 16-z tile index base
        bf16x8 af[4], bf[2];
#pragma unroll
        for (int mt = 0; mt < 4; mt++)
            af[mt] = __builtin_nontemporal_load(
                (const bf16x8*)(apk + abase + (size_t)(mt * 192 + T2 + q2) * 256 +
                                c * 16 + q1 * 8));
#pragma unroll
        for (int nt = 0; nt < 2; nt++)
            bf[nt] = *(const bf16x8*)(hnT + (size_t)(n0 + nt * 16 + c) * NN + kglob + q * 8);
#pragma unroll
        for (int mt = 0; mt < 4; mt++)
#pragma unroll
            for (int nt = 0; nt < 2; nt++)
                acc[mt][nt] = __builtin_amdgcn_mfma_f32_16x16x32_bf16(
                    af[mt], bf[nt], acc[mt][nt], 0, 0, 0);
    }

    if (kw == 1) {
#pragma unroll
        for (int mt = 0; mt < 4; mt++)
#pragma unroll
            for (int nt = 0; nt < 2; nt++)
#pragma unroll
                for (int r = 0; r < 4; r++)
                    red[nw][(mt * 16 + 4 * q + r) * 33 + nt * 16 + c] = acc[mt][nt][r];
    }
    __syncthreads();
    if (kw == 0) {
#pragma unroll
        for (int mt = 0; mt < 4; mt++)
#pragma unroll
            for (int r = 0; r < 4; r++) {
                int x = m0 + mt * 16 + 4 * q + r;
                float rcp = 1.f / fmaxf(denom[x * 4 + b], 1e-12f);
#pragma unroll
                for (int nt = 0; nt < 2; nt++) {
                    float s = acc[mt][nt][r] + red[nw][(mt * 16 + 4 * q + r) * 33 + nt * 16 + c];
                    aggn[(size_t)x * 1024 + b * 256 + n0 + nt * 16 + c] = f2bf(s * rcp);
                }
            }
    }
}

// ---------------- k4: fc_v + elu + residual + kl ----------------
__global__ __launch_bounds__(256) void k4_out(const short* __restrict__ aggn,
                                              const short* __restrict__ WvT,
                                              const float* __restrict__ bv,
                                              const float* __restrict__ h,
                                              const float* __restrict__ klsum,
                                              float* __restrict__ out) {
    int bx = blockIdx.x;
    int mt = bx >> 2, nb = bx & 3;
    int m0 = mt * 64, n0 = nb * 64;
    int tid = threadIdx.x, w = tid >> 6, lane = tid & 63, q = lane >> 4, c = lane & 15;
    int mrow = m0 + w * 16;
    f32x4 acc[4] = {{0, 0, 0, 0}, {0, 0, 0, 0}, {0, 0, 0, 0}, {0, 0, 0, 0}};
    for (int k0 = 0; k0 < 1024; k0 += 32) {
        bf16x8 af = *(const bf16x8*)(aggn + (mrow + c) * 1024 + k0 + q * 8);
#pragma unroll
        for (int nt = 0; nt < 4; nt++) {
            bf16x8 bf = *(const bf16x8*)(WvT + (n0 + nt * 16 + c) * 1024 + k0 + q * 8);
            acc[nt] = __builtin_amdgcn_mfma_f32_16x16x32_bf16(af, bf, acc[nt], 0, 0, 0);
        }
    }
#pragma unroll
    for (int nt = 0; nt < 4; nt++) {
        int col = n0 + nt * 16 + c;
        float bias = bv[col];
#pragma unroll
        for (int r = 0; r < 4; r++) {
            int row = mrow + 4 * q + r;
            float v = acc[nt][r] + bias;
            v = (v > 0.f) ? v : (__expf(v) - 1.f);  // elu
            out[row * 256 + col] = v + h[row * 256 + col];
        }
    }
    if (bx == 0 && tid == 0) out[786432] = klsum[0] * (1.0f / 9437184.0f);
}

extern "C" void kernel_launch(void* const* d_in, const int* in_sizes, int n_in,
                              void* d_out, int out_size, void* d_ws, size_t ws_size,
                              hipStream_t stream) {
    const float* h = (const float*)d_in[0];
    const float* gamma = (const float*)d_in[1];
    const float* beta = (const float*)d_in[2];
    const float* Wk = (const float*)d_in[3];
    const float* bk = (const float*)d_in[4];
    const float* Wmu = (const float*)d_in[5];
    const float* bmu = (const float*)d_in[6];
    const float* Wls = (const float*)d_in[7];
    const float* bls = (const float*)d_in[8];
    const float* Wv = (const float*)d_in[9];
    const float* bv = (const float*)d_in[10];
    const float* diff = (const float*)d_in[11];
    const float* eps = (const float*)d_in[12];
    float* out = (float*)d_out;

    char* p = (char*)d_ws;
    short* apk = (short*)p;    p += (size_t)75497472;  // a tile-packed, 75.5 MB
    float* denom = (float*)p;  p += 49152;             // + klsum contiguous
    float* klsum = (float*)p;  p += 4096;
    short* hn = (short*)p;     p += 1572864;
    short* hnT = (short*)p;    p += 1572864;
    short* kml = (short*)p;    p += 4718592;           // fragment-packed
    short* WTcat = (short*)p;  p += 393216;
    float* biasc = (float*)p;  p += 4096;
    short* WvT = (short*)p;    p += 524288;
    short* aggn = (short*)p;                           // 6291456; total ~90.6 MB

    k0_prep<<<165, 256, 0, stream>>>(Wk, Wmu, Wls, bk, bmu, bls, Wv, WTcat, biasc, WvT,
                                     denom);
    k1_ln<<<3072, 256, 0, stream>>>(h, gamma, beta, hn);
    k1b_tr<<<192, 256, 0, stream>>>(hn, hnT);
    k2_proj<<<576, 256, 0, stream>>>(hn, WTcat, biasc, kml);
    k3a_elem<<<48 * 48, 256, 0, stream>>>(kml, eps, diff, apk, denom, klsum);
    k3b_agg<<<48 * 4 * 4, 256, 0, stream>>>(apk, hnT, denom, aggn);
    k4_out<<<192, 256, 0, stream>>>(aggn, WvT, bv, h, klsum, out);
}